// Round 9
// baseline (4822.326 us; speedup 1.0000x reference)
//
#include <hip/hip_runtime.h>
#include <math.h>

#define NPTS    16384
#define DIM     128
#define KSEL    16
#define TSEL    18      // per-scanner sorted top list (16 + self + 1 margin)
#define NSCAN   8       // scanners per row (one per half-wave)
#define RPB     32      // rows per block
#define THREADS 256
#define CHUNK   128     // candidate columns staged per LDS chunk
#define NCHUNK  (NPTS / CHUNK)
#define NCAND   (NSCAN * TSEL)   // 144 candidates per row
#define CSTRIDE 145              // padded per-row stride

// BIT-EXACT numpy f32 pairwise-sum of x*x for one contiguous row of 128
// floats, SIMD path with AVX512 (nlanes=16, n = 8*16 exactly -> one pass):
//   m[i]  = fl32(x[i]*x[i])                  (separate umath multiply pass)
//   r_b   = m[16b .. 16b+15]                 (8 raw vector loads)
//   s     = ((r0+r1)+(r2+r3)) + ((r4+r5)+(r6+r7))      (lanewise tree)
//   _mm512_reduce_add_ps halving tree:
//   u[i]=s[i]+s[i+8]; v[i]=u[i]+u[i+4]; w[i]=v[i]+v[i+2]; total=w[0]+w[1]
__device__ __forceinline__ float np_sq_avx512(const float* __restrict__ x) {
    float s[16];
    #pragma unroll
    for (int L = 0; L < 16; ++L) {
        const float m0 = __fmul_rn(x[  0 + L], x[  0 + L]);
        const float m1 = __fmul_rn(x[ 16 + L], x[ 16 + L]);
        const float m2 = __fmul_rn(x[ 32 + L], x[ 32 + L]);
        const float m3 = __fmul_rn(x[ 48 + L], x[ 48 + L]);
        const float m4 = __fmul_rn(x[ 64 + L], x[ 64 + L]);
        const float m5 = __fmul_rn(x[ 80 + L], x[ 80 + L]);
        const float m6 = __fmul_rn(x[ 96 + L], x[ 96 + L]);
        const float m7 = __fmul_rn(x[112 + L], x[112 + L]);
        s[L] = __fadd_rn(
            __fadd_rn(__fadd_rn(m0, m1), __fadd_rn(m2, m3)),
            __fadd_rn(__fadd_rn(m4, m5), __fadd_rn(m6, m7)));
    }
    float u[8];
    #pragma unroll
    for (int i = 0; i < 8; ++i) u[i] = __fadd_rn(s[i], s[i + 8]);
    float v[4];
    #pragma unroll
    for (int i = 0; i < 4; ++i) v[i] = __fadd_rn(u[i], u[i + 4]);
    const float w0 = __fadd_rn(v[0], v[2]);
    const float w1 = __fadd_rn(v[1], v[3]);
    return __fadd_rn(w0, w1);
}

__global__ __launch_bounds__(THREADS, 2)
void knn_kernel(const float* __restrict__ X, int* __restrict__ out) {
    // 64 KB buffer: chunk staging during the scan; packed (dist32,idx) keys +
    // index dump during the epilogue.
    __shared__ __align__(16) char smem[CHUNK * DIM * sizeof(float)];
    float* lds = (float*)smem;
    unsigned long long* keys = (unsigned long long*)smem;
    int* di = (int*)(smem + RPB * CSTRIDE * sizeof(unsigned long long));

    const int tid = threadIdx.x;
    const int s   = tid >> 5;       // scanner 0..7
    const int r   = tid & 31;       // row-in-block 0..31
    const int row = blockIdx.x * RPB + r;

    // own row in registers (128 VGPRs)
    float4 xi4[32];
    {
        const float4* xr = (const float4*)(X + (size_t)row * DIM);
        #pragma unroll
        for (int g = 0; g < 32; ++g) xi4[g] = xr[g];
    }

    // np-replica sq of OWN row (exact numpy-AVX512 pairwise)
    const float sqi32 = np_sq_avx512(X + (size_t)row * DIM);

    // sorted ascending top-TSEL (fp32 scan key, candidate index) — capture only
    float bv[TSEL]; int bi[TSEL];
    #pragma unroll
    for (int k = 0; k < TSEL; ++k) { bv[k] = 3.0e38f; bi[k] = 0; }

    const float4* X4 = (const float4*)X;
    float4* lds4 = (float4*)smem;

    for (int c = 0; c < NCHUNK; ++c) {
        // ---- stage chunk (coalesced linear copy) ----
        #pragma unroll 4
        for (int q = 0; q < 16; ++q)
            lds4[tid + THREADS * q] =
                X4[(size_t)c * (CHUNK * DIM / 4) + tid + THREADS * q];
        __syncthreads();

        // ---- scan: scanner s handles j_local = s*16 + jj ----
        #pragma unroll 1
        for (int jj = 0; jj < 16; ++jj) {
            const int jl = s * 16 + jj;              // uniform per half-wave
            const float4* bp = (const float4*)(lds + jl * DIM);
            float dot = 0.f;
            #pragma unroll
            for (int g = 0; g < 32; ++g) {           // LDS broadcast reads
                const float4 b = bp[g];
                dot += b.x * xi4[g].x; dot += b.y * xi4[g].y;
                dot += b.z * xi4[g].z; dot += b.w * xi4[g].w;
            }
            // sq_j: 4 stride-32 reads (distinct banks) + half-wave reduce
            float p0 = lds[jl * DIM + r];
            float p1 = lds[jl * DIM + r + 32];
            float p2 = lds[jl * DIM + r + 64];
            float p3 = lds[jl * DIM + r + 96];
            float sq = p0 * p0 + p1 * p1 + p2 * p2 + p3 * p3;
            #pragma unroll
            for (int off = 16; off > 0; off >>= 1) sq += __shfl_xor(sq, off, 32);

            const float val = sq - 2.f * dot;        // capture key (noise ok)
            const int   jg  = c * CHUNK + jl;

            if (val < bv[TSEL - 1]) {                // rare after warm-up
                #pragma unroll
                for (int k = TSEL - 1; k >= 1; --k) {
                    const bool m1 = val < bv[k - 1];
                    const bool m2 = val < bv[k];
                    bv[k] = m1 ? bv[k - 1] : (m2 ? val : bv[k]);
                    bi[k] = m1 ? bi[k - 1] : (m2 ? jg  : bi[k]);
                }
                if (val < bv[0]) { bv[0] = val; bi[0] = jg; }
            }
        }
        __syncthreads();   // before next stage overwrites the buffer
    }
    // (last loop iteration ended with __syncthreads: all scans done)

    // ---- dump candidate indices ----
    #pragma unroll
    for (int k = 0; k < TSEL; ++k)
        di[r * CSTRIDE + s * TSEL + k] = bi[k];

    // ---- rescore: bit-replica of the np f32 pipeline ----
    //   sq_j : numpy pairwise-SIMD (AVX512) — np_sq_avx512 above
    //   dot  : serial k-order f32 FMA chain (OpenBLAS sgemm, 1 acc/element)
    //   d2   = fsub32( fadd32(sq_i, sq_j), fmul32(2, dot) )   [×2 exact]
    //   dist = sqrtf(max(d2,0))        [np.sqrt f32, correctly rounded]
    //   key  = (bits(dist)<<32) | idx  -> stable top_k (ties -> lower index)
    for (int k = 0; k < TSEL; ++k) {
        const int j = di[r * CSTRIDE + s * TSEL + k];
        unsigned long long key;
        if (j == row) {
            key = 0xFFFFFFFFFFFFFFFFULL;              // self: excluded
        } else {
            const float* xjp = X + (size_t)j * DIM;
            const float4* xj = (const float4*)xjp;
            // pass A: np-replica sq_j
            const float sqj32 = np_sq_avx512(xjp);
            // pass B: serial-FMA dot chain in strict k order
            float cacc = 0.f;
            #pragma unroll
            for (int g = 0; g < 32; ++g) {
                const float4 a = xi4[g], b = xj[g];
                cacc = __fmaf_rn(a.x, b.x, cacc);
                cacc = __fmaf_rn(a.y, b.y, cacc);
                cacc = __fmaf_rn(a.z, b.z, cacc);
                cacc = __fmaf_rn(a.w, b.w, cacc);
            }
            float d2c = __fsub_rn(__fadd_rn(sqi32, sqj32),
                                  __fmul_rn(2.0f, cacc));
            if (d2c < 0.0f) d2c = 0.0f;
            const float dist32 = sqrtf(d2c);          // f32 sqrt, correct rnd
            key = ((unsigned long long)__float_as_uint(dist32) << 32)
                  | (unsigned int)j;
        }
        keys[r * CSTRIDE + s * TSEL + k] = key;
    }
    __syncthreads();

    // ---- per-row top-16 by packed key ----
    if (tid < 32) {
        const int base = tid * CSTRIDE;
        const int i = blockIdx.x * RPB + tid;
        for (int m = 0; m < KSEL; ++m) {
            unsigned long long best = 0xFFFFFFFFFFFFFFFFULL; int bc = 0;
            for (int c2 = 0; c2 < NCAND; ++c2) {
                const unsigned long long v = keys[base + c2];
                if (v < best) { best = v; bc = c2; }
            }
            out[(size_t)i * KSEL + m] = (int)(best & 0xFFFFFFFFULL);
            keys[base + bc] = 0xFFFFFFFFFFFFFFFFULL;  // remove picked
        }
    }
}

extern "C" void kernel_launch(void* const* d_in, const int* in_sizes, int n_in,
                              void* d_out, int out_size, void* d_ws, size_t ws_size,
                              hipStream_t stream) {
    (void)in_sizes; (void)n_in; (void)out_size; (void)d_ws; (void)ws_size;
    const float* X = (const float*)d_in[0];
    int* out = (int*)d_out;
    knn_kernel<<<dim3(NPTS / RPB), dim3(THREADS), 0, stream>>>(X, out);
}